// Round 3
// baseline (487.116 us; speedup 1.0000x reference)
//
#include <hip/hip_runtime.h>

typedef __attribute__((ext_vector_type(8))) short short8;
typedef __attribute__((ext_vector_type(4))) float f32x4;
typedef __attribute__((ext_vector_type(4))) unsigned short us4;
typedef __attribute__((ext_vector_type(4))) unsigned int u32x4;

#define MFMA16(a,b,c) __builtin_amdgcn_mfma_f32_16x16x32_bf16(a,b,c,0,0,0)

#define EMBED 768
#define HEADS 12
#define DK 64
#define M_MISS 2048
#define N_EX 6144
#define NSEC 8192
#define NSPLIT 4
#define NSL (N_EX / NSPLIT)   // 1536 keys per split
#define DPHY 192              // physical packed dim: [0,64)=proj, [64,128)=bias_hi, [128,192)=bias_lo

__device__ __forceinline__ unsigned short f2bf(float f){
  unsigned u = __builtin_bit_cast(unsigned, f);
  u += 0x7FFFu + ((u >> 16) & 1u);
  return (unsigned short)(u >> 16);
}
__device__ __forceinline__ float bf2f(unsigned short h){
  return __builtin_bit_cast(float, ((unsigned)h) << 16);
}

// ---------------- transpose + cast weights: Wt[which][c][e] = W[e][c] ----------------
__global__ __launch_bounds__(256) void k_transpose_w(
    const float* __restrict__ Wq, const float* __restrict__ Wk,
    const float* __restrict__ Wv, unsigned short* __restrict__ Wt)
{
  int bid = blockIdx.x;
  int which = bid / 144, t = bid % 144;
  int er0 = (t / 12) * 64, cc0 = (t % 12) * 64;
  const float* W = (which == 0) ? Wq : ((which == 1) ? Wk : Wv);
  unsigned short* dst = Wt + (long)which * EMBED * EMBED;
  __shared__ float tile[64][65];
  int tid = threadIdx.x;
  {
    int e = tid >> 4, c4 = (tid & 15) * 4;
    for (int i = 0; i < 4; i++) {
      float4 v = *reinterpret_cast<const float4*>(&W[(long)(er0 + e + i*16) * EMBED + cc0 + c4]);
      tile[e + i*16][c4 + 0] = v.x; tile[e + i*16][c4 + 1] = v.y;
      tile[e + i*16][c4 + 2] = v.z; tile[e + i*16][c4 + 3] = v.w;
    }
  }
  __syncthreads();
  {
    int c = tid >> 4, e4 = (tid & 15) * 4;
    for (int i = 0; i < 4; i++) {
      us4 u;
      for (int j = 0; j < 4; j++) u[j] = f2bf(tile[e4 + j][c + i*16]);
      *reinterpret_cast<us4*>(&dst[(long)(cc0 + c + i*16) * EMBED + er0 + e4]) = u;
    }
  }
}

// ---------------- copy ehr -> out ----------------
__global__ __launch_bounds__(256) void k_copy(const float4* __restrict__ s, float4* __restrict__ d, int n){
  int g = blockIdx.x * 256 + threadIdx.x;
  if (g < n) d[g] = s[g];
}

// ---------------- gather cooc_bias, hi/lo split, into dims [64,192) of Qp/Kp ----------------
__global__ __launch_bounds__(256) void k_pack_cooc(
    const float* __restrict__ cooc, const int* __restrict__ idx, int count,
    unsigned short* __restrict__ dst)
{
  int g = blockIdx.x * 256 + threadIdx.x;
  int total = HEADS * count * 16;
  if (g >= total) return;
  int d4 = (g & 15) * 4;
  int r  = (g >> 4) % count;
  int h  = (g >> 4) / count;
  int src_row = idx[r];
  float4 v = *reinterpret_cast<const float4*>(&cooc[((long)h * NSEC + src_row) * DK + d4]);
  us4 hi, lo;
  float xs[4] = {v.x, v.y, v.z, v.w};
  #pragma unroll
  for (int j = 0; j < 4; j++) {
    unsigned short hb = f2bf(xs[j]);
    hi[j] = hb;
    lo[j] = f2bf(xs[j] - bf2f(hb));
  }
  long base = ((long)h * count + r) * DPHY;
  *reinterpret_cast<us4*>(&dst[base +  64 + d4]) = hi;
  *reinterpret_cast<us4*>(&dst[base + 128 + d4]) = lo;
}

// ---------------- gather-GEMM: gather(ehr,idx) @ W + b, packed per mode ----------------
// mode 0: Qp[h][m][d]*0.125, row stride DPHY    mode 1: Kp[h][n][d], row stride DPHY
// mode 2: Vt[h][d][n] (transposed for PV B-frags)
__global__ __launch_bounds__(256) void k_gemm_qkv(
    const float* __restrict__ ehr, const int* __restrict__ idx, int nrb,
    const unsigned short* __restrict__ Wt, const float* __restrict__ bias,
    unsigned short* __restrict__ dst, int mode)
{
  __shared__ unsigned char sA[128 * 64];
  __shared__ unsigned char sB[128 * 64];
  int tid = threadIdx.x;
  int rb = blockIdx.x % nrb, cb = blockIdx.x / nrb;
  int row0 = rb * 128, col0 = cb * 128;
  int wv = tid >> 6, lane = tid & 63, l15 = lane & 15, lg = lane >> 4;
  int wm = wv >> 1, wn = wv & 1;

  int ar = tid >> 2, as = tid & 3;
  long g0 = idx[row0 + ar];
  long g1 = idx[row0 + ar + 64];
  const float* ap0 = ehr + g0 * EMBED + as * 8;
  const float* ap1 = ehr + g1 * EMBED + as * 8;
  const unsigned short* bp0 = Wt + (long)(col0 + ar) * EMBED + as * 8;
  const unsigned short* bp1 = Wt + (long)(col0 + ar + 64) * EMBED + as * 8;
  unsigned aoff = (unsigned)ar * 64 + ((unsigned)(as ^ (ar & 3)) << 4);

  f32x4 acc[4][4];
  for (int i = 0; i < 4; i++) for (int j = 0; j < 4; j++) acc[i][j] = (f32x4){0.f,0.f,0.f,0.f};

  for (int k0 = 0; k0 < EMBED; k0 += 32) {
    __syncthreads();
    {
      float4 u0 = *reinterpret_cast<const float4*>(ap0 + k0);
      float4 u1 = *reinterpret_cast<const float4*>(ap0 + k0 + 4);
      short8 p;
      p[0]=(short)f2bf(u0.x); p[1]=(short)f2bf(u0.y); p[2]=(short)f2bf(u0.z); p[3]=(short)f2bf(u0.w);
      p[4]=(short)f2bf(u1.x); p[5]=(short)f2bf(u1.y); p[6]=(short)f2bf(u1.z); p[7]=(short)f2bf(u1.w);
      *reinterpret_cast<short8*>(&sA[aoff]) = p;
      u0 = *reinterpret_cast<const float4*>(ap1 + k0);
      u1 = *reinterpret_cast<const float4*>(ap1 + k0 + 4);
      p[0]=(short)f2bf(u0.x); p[1]=(short)f2bf(u0.y); p[2]=(short)f2bf(u0.z); p[3]=(short)f2bf(u0.w);
      p[4]=(short)f2bf(u1.x); p[5]=(short)f2bf(u1.y); p[6]=(short)f2bf(u1.z); p[7]=(short)f2bf(u1.w);
      *reinterpret_cast<short8*>(&sA[aoff + 64 * 64]) = p;
      *reinterpret_cast<short8*>(&sB[aoff]) = *reinterpret_cast<const short8*>(bp0 + k0);
      *reinterpret_cast<short8*>(&sB[aoff + 64 * 64]) = *reinterpret_cast<const short8*>(bp1 + k0);
    }
    __syncthreads();
    short8 a[4], b[4];
    for (int i = 0; i < 4; i++) {
      unsigned r = (unsigned)(wm * 64 + 16 * i + l15);
      a[i] = *reinterpret_cast<const short8*>(&sA[r * 64 + (((unsigned)lg ^ (r & 3)) << 4)]);
      unsigned c = (unsigned)(wn * 64 + 16 * i + l15);
      b[i] = *reinterpret_cast<const short8*>(&sB[c * 64 + (((unsigned)lg ^ (c & 3)) << 4)]);
    }
    for (int i = 0; i < 4; i++)
      for (int j = 0; j < 4; j++)
        acc[i][j] = MFMA16(a[i], b[j], acc[i][j]);
  }

  for (int i = 0; i < 4; i++) {
    int mrow = row0 + wm * 64 + 16 * i + lg * 4;
    for (int j = 0; j < 4; j++) {
      int cg = col0 + wn * 64 + 16 * j + l15;
      float bv = bias[cg];
      int h = cg >> 6, d = cg & 63;
      if (mode == 2) {
        us4 u;
        for (int r = 0; r < 4; r++) u[r] = f2bf(acc[i][j][r] + bv);
        *reinterpret_cast<us4*>(&dst[((long)h * 64 + d) * N_EX + mrow]) = u;
      } else if (mode == 0) {
        for (int r = 0; r < 4; r++)
          dst[((long)h * M_MISS + mrow + r) * DPHY + d] = f2bf((acc[i][j][r] + bv) * 0.125f);
      } else {
        for (int r = 0; r < 4; r++)
          dst[((long)h * N_EX + mrow + r) * DPHY + d] = f2bf(acc[i][j][r] + bv);
      }
    }
  }
}

// ---------------- flash attention, split-KV, hi/lo bias split, in-register P ----------------
// grid 768 = 12h x 4sp x 16qb. 4 waves x 32 q-rows = 128 Q rows/block. KVBLK=64, 24 iters.
// Logical D_qk = 256 from 192 physical: products q.k + hi.hi + lo.hi + hi.lo.
// Natural-log-domain softmax (__expf), fp32 partials Opart/ML.
__global__ __launch_bounds__(256) void k_attn(
    const unsigned short* __restrict__ Qp, const unsigned short* __restrict__ Kp,
    const unsigned short* __restrict__ Vt,
    float* __restrict__ Opart, float* __restrict__ ML)
{
  // XCD-chunked swizzle: 768 = 8 XCDs x 96; consecutive wg share (h,sp) K/V slice
  int wg = (blockIdx.x & 7) * 96 + (blockIdx.x >> 3);
  int h  = wg >> 6;
  int sp = (wg >> 4) & 3;
  int qb = wg & 15;
  int tid = threadIdx.x;
  int wv = tid >> 6, lane = tid & 63, l15 = lane & 15, lg = lane >> 4;

  __shared__ unsigned char sK[64 * 384];   // 64 n-rows x 192 bf16 (24 slots of 16B), swizzled
  __shared__ unsigned char sV[64 * 128];   // 64 d-rows x  64 bf16 ( 8 slots), swizzled

  int mbase = qb * 128 + wv * 32;

  // Q as B-operand fragments (col = m = l15, k-chunk = lg*8), 6 physical chunks
  short8 qf[2][6];
  #pragma unroll
  for (int ms = 0; ms < 2; ms++) {
    const unsigned short* qrow = Qp + ((long)h * M_MISS + mbase + ms*16 + l15) * DPHY + lg * 8;
    #pragma unroll
    for (int t = 0; t < 6; t++)
      qf[ms][t] = *reinterpret_cast<const short8*>(qrow + t * 32);
  }

  f32x4 oacc[2][4];
  #pragma unroll
  for (int ms = 0; ms < 2; ms++)
    #pragma unroll
    for (int ds = 0; ds < 4; ds++) oacc[ms][ds] = (f32x4){0.f,0.f,0.f,0.f};
  float m_run[2] = {-3.0e38f, -3.0e38f};
  float l_run[2] = {0.f, 0.f};

  const unsigned short* kti0 = Kp + ((long)h * N_EX + sp * NSL) * DPHY;
  const unsigned short* vti0 = Vt + (long)h * 64 * N_EX + sp * NSL;
  int sla = l15 + ((lane & 16) << 1);   // l15 + 32*(lg&1)
  int slb = sla + 16;

  for (int it = 0; it < NSL / 64; ++it) {
    __syncthreads();
    {
      const unsigned short* kti = kti0 + (long)it * 64 * DPHY;
      #pragma unroll
      for (int i = 0; i < 6; i++) {           // 1536 16B-chunks of sK
        int c = i * 256 + tid;
        int row = c / 24, sl = c - row * 24;
        short8 v = *reinterpret_cast<const short8*>(kti + row * DPHY + sl * 8);
        *reinterpret_cast<short8*>(&sK[row * 384 + (((unsigned)sl ^ ((unsigned)row & 7)) << 4)]) = v;
      }
      const unsigned short* vti = vti0 + it * 64;
      #pragma unroll
      for (int i = 0; i < 2; i++) {           // 512 16B-chunks of sV
        int c = i * 256 + tid;
        int row = c >> 3, sl = c & 7;
        short8 v = *reinterpret_cast<const short8*>(vti + (long)row * N_EX + sl * 8);
        *reinterpret_cast<short8*>(&sV[row * 128 + (((unsigned)sl ^ ((unsigned)row & 7)) << 4)]) = v;
      }
    }
    __syncthreads();

    // S^T tiles: st[ns][ms], lane holds n = ns*16 + lg*4 + r, m = mbase + ms*16 + l15
    f32x4 st[4][2];
    #pragma unroll
    for (int ns = 0; ns < 4; ns++) { st[ns][0] = (f32x4){0.f,0.f,0.f,0.f}; st[ns][1] = (f32x4){0.f,0.f,0.f,0.f}; }
    #pragma unroll
    for (int ns = 0; ns < 4; ns++) {
      unsigned kr = (unsigned)(ns * 16 + l15);
      unsigned rb = kr * 384, px = kr & 7;
      short8 kf;
      // kc0 -> q0 ; kc1 -> q1 ; kc2 -> {q2,q4} ; kc3 -> {q3,q5} ; kc4 -> q2 ; kc5 -> q3
      kf = *reinterpret_cast<const short8*>(&sK[rb + ((((unsigned)(0*4+lg)) ^ px) << 4)]);
      st[ns][0] = MFMA16(kf, qf[0][0], st[ns][0]); st[ns][1] = MFMA16(kf, qf[1][0], st[ns][1]);
      kf = *reinterpret_cast<const short8*>(&sK[rb + ((((unsigned)(1*4+lg)) ^ px) << 4)]);
      st[ns][0] = MFMA16(kf, qf[0][1], st[ns][0]); st[ns][1] = MFMA16(kf, qf[1][1], st[ns][1]);
      kf = *reinterpret_cast<const short8*>(&sK[rb + ((((unsigned)(2*4+lg)) ^ px) << 4)]);
      st[ns][0] = MFMA16(kf, qf[0][2], st[ns][0]); st[ns][1] = MFMA16(kf, qf[1][2], st[ns][1]);
      st[ns][0] = MFMA16(kf, qf[0][4], st[ns][0]); st[ns][1] = MFMA16(kf, qf[1][4], st[ns][1]);
      kf = *reinterpret_cast<const short8*>(&sK[rb + ((((unsigned)(3*4+lg)) ^ px) << 4)]);
      st[ns][0] = MFMA16(kf, qf[0][3], st[ns][0]); st[ns][1] = MFMA16(kf, qf[1][3], st[ns][1]);
      st[ns][0] = MFMA16(kf, qf[0][5], st[ns][0]); st[ns][1] = MFMA16(kf, qf[1][5], st[ns][1]);
      kf = *reinterpret_cast<const short8*>(&sK[rb + ((((unsigned)(4*4+lg)) ^ px) << 4)]);
      st[ns][0] = MFMA16(kf, qf[0][2], st[ns][0]); st[ns][1] = MFMA16(kf, qf[1][2], st[ns][1]);
      kf = *reinterpret_cast<const short8*>(&sK[rb + ((((unsigned)(5*4+lg)) ^ px) << 4)]);
      st[ns][0] = MFMA16(kf, qf[0][3], st[ns][0]); st[ns][1] = MFMA16(kf, qf[1][3], st[ns][1]);
    }

    // online softmax (natural domain); pack P^T to bf16 pairs in-register
    unsigned pb[2][4][2];
    #pragma unroll
    for (int ms = 0; ms < 2; ms++) {
      float mx = st[0][ms][0];
      #pragma unroll
      for (int ns = 0; ns < 4; ns++)
        #pragma unroll
        for (int r = 0; r < 4; r++)
          if (ns | r) mx = fmaxf(mx, st[ns][ms][r]);
      mx = fmaxf(mx, __shfl_xor(mx, 16));
      mx = fmaxf(mx, __shfl_xor(mx, 32));
      float mn = fmaxf(m_run[ms], mx);
      float sc = __expf(m_run[ms] - mn);
      m_run[ms] = mn;
      float lsum = 0.f;
      float p[4][4];
      #pragma unroll
      for (int ns = 0; ns < 4; ns++)
        #pragma unroll
        for (int r = 0; r < 4; r++) {
          p[ns][r] = __expf(st[ns][ms][r] - mn);
          lsum += p[ns][r];
        }
      lsum += __shfl_xor(lsum, 16);
      lsum += __shfl_xor(lsum, 32);
      l_run[ms] = l_run[ms] * sc + lsum;
      #pragma unroll
      for (int ds = 0; ds < 4; ds++) oacc[ms][ds] *= sc;
      #pragma unroll
      for (int ns = 0; ns < 4; ns++) {
        pb[ms][ns][0] = (unsigned)f2bf(p[ns][0]) | ((unsigned)f2bf(p[ns][1]) << 16);
        pb[ms][ns][1] = (unsigned)f2bf(p[ns][2]) | ((unsigned)f2bf(p[ns][3]) << 16);
      }
    }

    // O^T += V^T . P^T : P^T B-frags via shfl, V^T A-frags from sV
    #pragma unroll
    for (int t2 = 0; t2 < 2; t2++) {
      short8 pf[2];
      #pragma unroll
      for (int ms = 0; ms < 2; ms++) {
        unsigned lo0 = (unsigned)__shfl((int)pb[ms][t2*2  ][0], sla);
        unsigned hi0 = (unsigned)__shfl((int)pb[ms][t2*2+1][0], sla);
        unsigned lo1 = (unsigned)__shfl((int)pb[ms][t2*2  ][1], sla);
        unsigned hi1 = (unsigned)__shfl((int)pb[ms][t2*2+1][1], sla);
        unsigned lo2 = (unsigned)__shfl((int)pb[ms][t2*2  ][0], slb);
        unsigned hi2 = (unsigned)__shfl((int)pb[ms][t2*2+1][0], slb);
        unsigned lo3 = (unsigned)__shfl((int)pb[ms][t2*2  ][1], slb);
        unsigned hi3 = (unsigned)__shfl((int)pb[ms][t2*2+1][1], slb);
        bool sh = (lane & 32) != 0;
        u32x4 w;
        w[0] = sh ? hi0 : lo0;
        w[1] = sh ? hi1 : lo1;
        w[2] = sh ? hi2 : lo2;
        w[3] = sh ? hi3 : lo3;
        pf[ms] = __builtin_bit_cast(short8, w);
      }
      #pragma unroll
      for (int ds = 0; ds < 4; ds++) {
        unsigned vr = (unsigned)(ds * 16 + l15);
        short8 vf = *reinterpret_cast<const short8*>(&sV[vr * 128 + ((((unsigned)(t2*4+lg)) ^ (vr & 7)) << 4)]);
        oacc[0][ds] = MFMA16(vf, pf[0], oacc[0][ds]);
        oacc[1][ds] = MFMA16(vf, pf[1], oacc[1][ds]);
      }
    }
  }

  // epilogue: fp32 partials. oacc[ms][ds]: m = mbase+ms*16+l15, d = ds*16+lg*4+r
  long pbase = ((long)(h * NSPLIT + sp)) * M_MISS;
  #pragma unroll
  for (int ms = 0; ms < 2; ms++) {
    int m = mbase + ms * 16 + l15;
    if (lg == 0) {
      float2 v; v.x = m_run[ms]; v.y = l_run[ms];
      *reinterpret_cast<float2*>(&ML[(pbase + m) * 2]) = v;
    }
    #pragma unroll
    for (int ds = 0; ds < 4; ds++)
      *reinterpret_cast<f32x4*>(&Opart[(pbase + m) * 64 + ds * 16 + lg * 4]) = oacc[ms][ds];
  }
}

// ---------------- merge split-KV partials, scatter to out ----------------
__global__ __launch_bounds__(256) void k_merge(
    const float* __restrict__ Opart, const float* __restrict__ ML,
    const int* __restrict__ missing, float* __restrict__ out)
{
  int g = blockIdx.x * 256 + threadIdx.x;   // HEADS*M_MISS*16
  int d4 = (g & 15) * 4;
  int row = g >> 4;
  int m = row & (M_MISS - 1), h = row >> 11;
  long b0 = (long)h * NSPLIT * M_MISS + m;
  float mm[NSPLIT], ll[NSPLIT];
  #pragma unroll
  for (int sp = 0; sp < NSPLIT; sp++) {
    float2 v = *reinterpret_cast<const float2*>(&ML[(b0 + (long)sp * M_MISS) * 2]);
    mm[sp] = v.x; ll[sp] = v.y;
  }
  float M = fmaxf(fmaxf(mm[0], mm[1]), fmaxf(mm[2], mm[3]));
  float L = 0.f;
  f32x4 o = (f32x4){0.f,0.f,0.f,0.f};
  #pragma unroll
  for (int sp = 0; sp < NSPLIT; sp++) {
    float w = __expf(mm[sp] - M);
    L += ll[sp] * w;
    f32x4 t = *reinterpret_cast<const f32x4*>(&Opart[(b0 + (long)sp * M_MISS) * 64 + d4]);
    o += t * w;
  }
  float inv = 1.0f / L;
  int orow = missing[m];
  *reinterpret_cast<f32x4*>(&out[(long)orow * EMBED + h * 64 + d4]) = o * inv;
}

extern "C" void kernel_launch(void* const* d_in, const int* in_sizes, int n_in,
                              void* d_out, int out_size, void* d_ws, size_t ws_size,
                              hipStream_t stream) {
  const float* ehr     = (const float*)d_in[0];
  const int*   exist   = (const int*)  d_in[1];
  const int*   missing = (const int*)  d_in[2];
  const float* Wq = (const float*)d_in[3];
  const float* bq = (const float*)d_in[4];
  const float* Wk = (const float*)d_in[5];
  const float* bk = (const float*)d_in[6];
  const float* Wv = (const float*)d_in[7];
  const float* bv = (const float*)d_in[8];
  const float* cooc = (const float*)d_in[9];
  float* out = (float*)d_out;

  char* ws = (char*)d_ws;
  // Wt (3.54 MB) is dead once the GEMMs finish; Opart (written later by k_attn) aliases it.
  unsigned short* Wt = (unsigned short*)(ws);                    // [0, 3,538,944)
  float*          Op = (float*)(ws);                             // [0, 25,165,824)  12*4*2048*64*4
  unsigned short* Qp = (unsigned short*)(ws + 25165824);         // 12*2048*192*2 =  9,437,184
  unsigned short* Kp = (unsigned short*)(ws + 34603008);         // 12*6144*192*2 = 28,311,552
  unsigned short* Vt = (unsigned short*)(ws + 62914560);         // 12*64*6144*2  =  9,437,184
  float*          Ml = (float*)(ws + 72351744);                  // 12*4*2048*2*4 =    786,432
                                                                 // total 73,138,176 bytes

  k_transpose_w<<<432, 256, 0, stream>>>(Wq, Wk, Wv, Wt);
  k_copy<<<(NSEC * EMBED / 4 + 255) / 256, 256, 0, stream>>>(
      (const float4*)ehr, (float4*)out, NSEC * EMBED / 4);
  k_pack_cooc<<<(HEADS * M_MISS * 16 + 255) / 256, 256, 0, stream>>>(cooc, missing, M_MISS, Qp);
  k_pack_cooc<<<(HEADS * N_EX * 16 + 255) / 256, 256, 0, stream>>>(cooc, exist, N_EX, Kp);
  k_gemm_qkv<<<(M_MISS / 128) * 6, 256, 0, stream>>>(ehr, missing, M_MISS / 128, Wt,               bq, Qp, 0);
  k_gemm_qkv<<<(N_EX  / 128) * 6, 256, 0, stream>>>(ehr, exist,   N_EX  / 128, Wt + 768 * 768,     bk, Kp, 1);
  k_gemm_qkv<<<(N_EX  / 128) * 6, 256, 0, stream>>>(ehr, exist,   N_EX  / 128, Wt + 2 * 768 * 768, bv, Vt, 2);
  k_attn<<<HEADS * NSPLIT * (M_MISS / 128), 256, 0, stream>>>(Qp, Kp, Vt, Op, Ml);
  k_merge<<<HEADS * M_MISS * 16 / 256, 256, 0, stream>>>(Op, Ml, missing, out);
}

// Round 4
// 213.022 us; speedup vs baseline: 2.2867x; 2.2867x over previous
//
#include <hip/hip_runtime.h>

typedef __attribute__((ext_vector_type(8))) short short8;
typedef __attribute__((ext_vector_type(4))) float f32x4;
typedef __attribute__((ext_vector_type(4))) unsigned short us4;
typedef __attribute__((ext_vector_type(4))) unsigned int u32x4;

#define MFMA16(a,b,c) __builtin_amdgcn_mfma_f32_16x16x32_bf16(a,b,c,0,0,0)

#define EMBED 768
#define HEADS 12
#define DK 64
#define M_MISS 2048
#define N_EX 6144
#define NSEC 8192
#define NSPLIT 4
#define NSL (N_EX / NSPLIT)   // 1536 keys per split
#define DPHY 192              // physical packed dim: [0,64)=proj, [64,128)=bias_hi, [128,192)=bias_lo

// direct global->LDS, 16B per lane; dest = wave-uniform base + lane*16
#define GLOAD16(g, l) __builtin_amdgcn_global_load_lds( \
    (const __attribute__((address_space(1))) unsigned int*)(g), \
    (__attribute__((address_space(3))) unsigned int*)(l), 16, 0, 0)

__device__ __forceinline__ unsigned short f2bf(float f){
  unsigned u = __builtin_bit_cast(unsigned, f);
  u += 0x7FFFu + ((u >> 16) & 1u);
  return (unsigned short)(u >> 16);
}
__device__ __forceinline__ float bf2f(unsigned short h){
  return __builtin_bit_cast(float, ((unsigned)h) << 16);
}

// ---------------- prep: out <- ehr (fp32 copy), ehrb <- bf16(ehr) ----------------
__global__ __launch_bounds__(256) void k_prep(
    const float* __restrict__ ehr, float* __restrict__ out, unsigned short* __restrict__ ehrb)
{
  int g = blockIdx.x * 256 + threadIdx.x;   // 786432 threads, 8 elems each
  float4 v0 = *reinterpret_cast<const float4*>(&ehr[(long)g * 8]);
  float4 v1 = *reinterpret_cast<const float4*>(&ehr[(long)g * 8 + 4]);
  *reinterpret_cast<float4*>(&out[(long)g * 8]) = v0;
  *reinterpret_cast<float4*>(&out[(long)g * 8 + 4]) = v1;
  short8 p;
  p[0]=(short)f2bf(v0.x); p[1]=(short)f2bf(v0.y); p[2]=(short)f2bf(v0.z); p[3]=(short)f2bf(v0.w);
  p[4]=(short)f2bf(v1.x); p[5]=(short)f2bf(v1.y); p[6]=(short)f2bf(v1.z); p[7]=(short)f2bf(v1.w);
  *reinterpret_cast<short8*>(&ehrb[(long)g * 8]) = p;
}

// ---------------- transpose + cast weights: Wt[which][c][e] = W[e][c] ----------------
__global__ __launch_bounds__(256) void k_transpose_w(
    const float* __restrict__ Wq, const float* __restrict__ Wk,
    const float* __restrict__ Wv, unsigned short* __restrict__ Wt)
{
  int bid = blockIdx.x;
  int which = bid / 144, t = bid % 144;
  int er0 = (t / 12) * 64, cc0 = (t % 12) * 64;
  const float* W = (which == 0) ? Wq : ((which == 1) ? Wk : Wv);
  unsigned short* dst = Wt + (long)which * EMBED * EMBED;
  __shared__ float tile[64][65];
  int tid = threadIdx.x;
  {
    int e = tid >> 4, c4 = (tid & 15) * 4;
    for (int i = 0; i < 4; i++) {
      float4 v = *reinterpret_cast<const float4*>(&W[(long)(er0 + e + i*16) * EMBED + cc0 + c4]);
      tile[e + i*16][c4 + 0] = v.x; tile[e + i*16][c4 + 1] = v.y;
      tile[e + i*16][c4 + 2] = v.z; tile[e + i*16][c4 + 3] = v.w;
    }
  }
  __syncthreads();
  {
    int c = tid >> 4, e4 = (tid & 15) * 4;
    for (int i = 0; i < 4; i++) {
      us4 u;
      for (int j = 0; j < 4; j++) u[j] = f2bf(tile[e4 + j][c + i*16]);
      *reinterpret_cast<us4*>(&dst[(long)(cc0 + c + i*16) * EMBED + er0 + e4]) = u;
    }
  }
}

// ---------------- gather cooc_bias, hi/lo split, into dims [64,192) of Qp/Kp ----------------
__global__ __launch_bounds__(256) void k_pack_cooc(
    const float* __restrict__ cooc, const int* __restrict__ idx, int count,
    unsigned short* __restrict__ dst)
{
  int g = blockIdx.x * 256 + threadIdx.x;
  int total = HEADS * count * 16;
  if (g >= total) return;
  int d4 = (g & 15) * 4;
  int r  = (g >> 4) % count;
  int h  = (g >> 4) / count;
  int src_row = idx[r];
  float4 v = *reinterpret_cast<const float4*>(&cooc[((long)h * NSEC + src_row) * DK + d4]);
  us4 hi, lo;
  float xs[4] = {v.x, v.y, v.z, v.w};
  #pragma unroll
  for (int j = 0; j < 4; j++) {
    unsigned short hb = f2bf(xs[j]);
    hi[j] = hb;
    lo[j] = f2bf(xs[j] - bf2f(hb));
  }
  long base = ((long)h * count + r) * DPHY;
  *reinterpret_cast<us4*>(&dst[base +  64 + d4]) = hi;
  *reinterpret_cast<us4*>(&dst[base + 128 + d4]) = lo;
}

// ---------------- fused gather-GEMM (Q/K/V in one launch), gload_lds staging ----------------
// mode 0 (bid<96):    Qp[h][m][d] = (x@Wq+bq)*0.125, row stride DPHY
// mode 1 (96..384):   Kp[h][n][d] =  x@Wk+bk,        row stride DPHY
// mode 2 (384..672):  Vt[h][d][n] =  x@Wv+bv         (transposed)
__global__ __launch_bounds__(256) void k_gemm_fused(
    const unsigned short* __restrict__ ehrb,
    const int* __restrict__ missing, const int* __restrict__ exist,
    const unsigned short* __restrict__ Wt,
    const float* __restrict__ bq, const float* __restrict__ bk, const float* __restrict__ bv,
    unsigned short* __restrict__ Qp, unsigned short* __restrict__ Kp, unsigned short* __restrict__ Vt)
{
  __shared__ unsigned char sA[2][8192];   // 128 rows x 32 bf16 (64B rows), chunk-swizzled
  __shared__ unsigned char sB[2][8192];
  int bid = blockIdx.x;
  int mode, row0, col0;
  const int* idx; const unsigned short* W; const float* bias;
  if (bid < 96)       { mode = 0; idx = missing; W = Wt;              bias = bq;
                        row0 = (bid & 15) * 128; col0 = (bid >> 4) * 128; }
  else if (bid < 384) { int t = bid - 96;  mode = 1; idx = exist; W = Wt + 589824;     bias = bk;
                        row0 = (t % 48) * 128; col0 = (t / 48) * 128; }
  else                { int t = bid - 384; mode = 2; idx = exist; W = Wt + 2 * 589824; bias = bv;
                        row0 = (t % 48) * 128; col0 = (t / 48) * 128; }

  int tid = threadIdx.x;
  int wv4 = tid >> 6, lane = tid & 63, l15 = lane & 15, lg = lane >> 4;
  int wm = wv4 >> 1, wn = wv4 & 1;

  // staging: chunk s = issue*256 + tid -> row = s>>2, slot = s&3 (16B chunks, 4/row)
  // LDS linear dest s*16; global source pre-swizzled: chunk slot^(row&3)
  int ar = tid >> 2, sl = tid & 3;
  int aoff = (sl ^ (ar & 3)) << 3;                     // element offset within row
  long gA0 = (long)idx[row0 + ar] * EMBED + aoff;
  long gA1 = (long)idx[row0 + ar + 64] * EMBED + aoff; // (ar+64)&3 == ar&3
  long gB0 = (long)(col0 + ar) * EMBED + aoff;
  long gB1 = gB0 + (long)64 * EMBED;

  f32x4 acc[4][4];
  #pragma unroll
  for (int i = 0; i < 4; i++)
    #pragma unroll
    for (int j = 0; j < 4; j++) acc[i][j] = (f32x4){0.f,0.f,0.f,0.f};

  #define STAGE_G(buf, k0) do { \
    GLOAD16(ehrb + gA0 + (k0), &sA[buf][wv4 * 1024]); \
    GLOAD16(ehrb + gA1 + (k0), &sA[buf][4096 + wv4 * 1024]); \
    GLOAD16(W + gB0 + (k0), &sB[buf][wv4 * 1024]); \
    GLOAD16(W + gB1 + (k0), &sB[buf][4096 + wv4 * 1024]); \
  } while (0)

  STAGE_G(0, 0);
  __syncthreads();
  int cur = 0;
  for (int ks = 0; ks < 24; ks++) {
    if (ks < 23) STAGE_G(cur ^ 1, (ks + 1) * 32);
    short8 a[4], b[4];
    #pragma unroll
    for (int i = 0; i < 4; i++) {
      unsigned r = (unsigned)(wm * 64 + 16 * i + l15);
      a[i] = *reinterpret_cast<const short8*>(&sA[cur][r * 64 + (((unsigned)lg ^ (r & 3)) << 4)]);
      unsigned c = (unsigned)(wn * 64 + 16 * i + l15);
      b[i] = *reinterpret_cast<const short8*>(&sB[cur][c * 64 + (((unsigned)lg ^ (c & 3)) << 4)]);
    }
    #pragma unroll
    for (int i = 0; i < 4; i++)
      #pragma unroll
      for (int j = 0; j < 4; j++)
        acc[i][j] = MFMA16(a[i], b[j], acc[i][j]);
    __syncthreads();
    cur ^= 1;
  }
  #undef STAGE_G

  #pragma unroll
  for (int i = 0; i < 4; i++) {
    int mrow = row0 + wm * 64 + 16 * i + lg * 4;
    #pragma unroll
    for (int j = 0; j < 4; j++) {
      int cg = col0 + wn * 64 + 16 * j + l15;
      float bv_ = bias[cg];
      int h = cg >> 6, d = cg & 63;
      if (mode == 2) {
        us4 u;
        #pragma unroll
        for (int r = 0; r < 4; r++) u[r] = f2bf(acc[i][j][r] + bv_);
        *reinterpret_cast<us4*>(&Vt[((long)h * 64 + d) * N_EX + mrow]) = u;
      } else if (mode == 0) {
        #pragma unroll
        for (int r = 0; r < 4; r++)
          Qp[((long)h * M_MISS + mrow + r) * DPHY + d] = f2bf((acc[i][j][r] + bv_) * 0.125f);
      } else {
        #pragma unroll
        for (int r = 0; r < 4; r++)
          Kp[((long)h * N_EX + mrow + r) * DPHY + d] = f2bf(acc[i][j][r] + bv_);
      }
    }
  }
}

// ---------------- flash attention, split-KV, hi/lo bias, gload_lds dbuf pipeline ----------------
// grid 768 = 12h x 4sp x 16qb. 4 waves x 32 q-rows = 128 Q rows/block. KVBLK=64, 24 iters.
// Logical D_qk = 256 from 192 physical: q.k + hi.hi + lo.hi + hi.lo.
__global__ __launch_bounds__(256) void k_attn(
    const unsigned short* __restrict__ Qp, const unsigned short* __restrict__ Kp,
    const unsigned short* __restrict__ Vt,
    float* __restrict__ Opart, float* __restrict__ ML)
{
  // XCD-chunked swizzle: 768 = 8 XCDs x 96; consecutive wg share (h,sp) K/V slice
  int wg = (blockIdx.x & 7) * 96 + (blockIdx.x >> 3);
  int h  = wg >> 6;
  int sp = (wg >> 4) & 3;
  int qb = wg & 15;
  int tid = threadIdx.x;
  int wv = tid >> 6, lane = tid & 63, l15 = lane & 15, lg = lane >> 4;

  __shared__ unsigned char sK[2][64 * 384];   // 64 n-rows x 192 bf16 (24 chunks), swizzled
  __shared__ unsigned char sV[2][64 * 128];   // 64 d-rows x  64 bf16 ( 8 chunks), swizzled

  // staging offsets: K chunk s = i*256+tid -> row=s/24, slot=s%24; source pre-swizzled
  int koff[6];
  #pragma unroll
  for (int i = 0; i < 6; i++) {
    int s = i * 256 + tid;
    int row = s / 24, slt = s - row * 24;
    koff[i] = row * DPHY + ((slt ^ (row & 7)) << 3);
  }
  int voff[2];
  #pragma unroll
  for (int i = 0; i < 2; i++) {
    int s = i * 256 + tid;
    int row = s >> 3, slt = s & 7;
    voff[i] = row * N_EX + ((slt ^ (row & 7)) << 3);
  }
  const unsigned short* kti0 = Kp + ((long)h * N_EX + sp * NSL) * DPHY;
  const unsigned short* vti0 = Vt + (long)h * 64 * N_EX + sp * NSL;

  #define STAGE_KV(buf, it) do { \
    const unsigned short* kt_ = kti0 + (long)(it) * 64 * DPHY; \
    GLOAD16(kt_ + koff[0], &sK[buf][(0 * 4 + wv) * 1024]); \
    GLOAD16(kt_ + koff[1], &sK[buf][(1 * 4 + wv) * 1024]); \
    GLOAD16(kt_ + koff[2], &sK[buf][(2 * 4 + wv) * 1024]); \
    GLOAD16(kt_ + koff[3], &sK[buf][(3 * 4 + wv) * 1024]); \
    GLOAD16(kt_ + koff[4], &sK[buf][(4 * 4 + wv) * 1024]); \
    GLOAD16(kt_ + koff[5], &sK[buf][(5 * 4 + wv) * 1024]); \
    const unsigned short* vt_ = vti0 + (it) * 64; \
    GLOAD16(vt_ + voff[0], &sV[buf][(0 * 4 + wv) * 1024]); \
    GLOAD16(vt_ + voff[1], &sV[buf][(1 * 4 + wv) * 1024]); \
  } while (0)

  int mbase = qb * 128 + wv * 32;

  // Q as B-operand fragments (col = m = l15, k-chunk = lg*8), 6 physical chunks
  short8 qf[2][6];
  #pragma unroll
  for (int ms = 0; ms < 2; ms++) {
    const unsigned short* qrow = Qp + ((long)h * M_MISS + mbase + ms*16 + l15) * DPHY + lg * 8;
    #pragma unroll
    for (int t = 0; t < 6; t++)
      qf[ms][t] = *reinterpret_cast<const short8*>(qrow + t * 32);
  }

  f32x4 oacc[2][4];
  #pragma unroll
  for (int ms = 0; ms < 2; ms++)
    #pragma unroll
    for (int ds = 0; ds < 4; ds++) oacc[ms][ds] = (f32x4){0.f,0.f,0.f,0.f};
  float m_run[2] = {-3.0e38f, -3.0e38f};
  float l_run[2] = {0.f, 0.f};

  int sla = l15 + ((lane & 16) << 1);   // l15 + 32*(lg&1)
  int slb = sla + 16;

  STAGE_KV(0, 0);
  __syncthreads();
  int cur = 0;

  for (int it = 0; it < NSL / 64; ++it) {
    if (it + 1 < NSL / 64) STAGE_KV(cur ^ 1, it + 1);

    // S^T tiles: st[ns][ms], lane holds n = ns*16 + lg*4 + r, m = mbase + ms*16 + l15
    f32x4 st[4][2];
    #pragma unroll
    for (int ns = 0; ns < 4; ns++) { st[ns][0] = (f32x4){0.f,0.f,0.f,0.f}; st[ns][1] = (f32x4){0.f,0.f,0.f,0.f}; }
    #pragma unroll
    for (int ns = 0; ns < 4; ns++) {
      unsigned kr = (unsigned)(ns * 16 + l15);
      unsigned rb = kr * 384, px = kr & 7;
      short8 kf;
      // kc0 -> q0 ; kc1 -> q1 ; kc2 -> {q2,q4} ; kc3 -> {q3,q5} ; kc4 -> q2 ; kc5 -> q3
      kf = *reinterpret_cast<const short8*>(&sK[cur][rb + ((((unsigned)(0*4+lg)) ^ px) << 4)]);
      st[ns][0] = MFMA16(kf, qf[0][0], st[ns][0]); st[ns][1] = MFMA16(kf, qf[1][0], st[ns][1]);
      kf = *reinterpret_cast<const short8*>(&sK[cur][rb + ((((unsigned)(1*4+lg)) ^ px) << 4)]);
      st[ns][0] = MFMA16(kf, qf[0][1], st[ns][0]); st[ns][1] = MFMA16(kf, qf[1][1], st[ns][1]);
      kf = *reinterpret_cast<const short8*>(&sK[cur][rb + ((((unsigned)(2*4+lg)) ^ px) << 4)]);
      st[ns][0] = MFMA16(kf, qf[0][2], st[ns][0]); st[ns][1] = MFMA16(kf, qf[1][2], st[ns][1]);
      st[ns][0] = MFMA16(kf, qf[0][4], st[ns][0]); st[ns][1] = MFMA16(kf, qf[1][4], st[ns][1]);
      kf = *reinterpret_cast<const short8*>(&sK[cur][rb + ((((unsigned)(3*4+lg)) ^ px) << 4)]);
      st[ns][0] = MFMA16(kf, qf[0][3], st[ns][0]); st[ns][1] = MFMA16(kf, qf[1][3], st[ns][1]);
      st[ns][0] = MFMA16(kf, qf[0][5], st[ns][0]); st[ns][1] = MFMA16(kf, qf[1][5], st[ns][1]);
      kf = *reinterpret_cast<const short8*>(&sK[cur][rb + ((((unsigned)(4*4+lg)) ^ px) << 4)]);
      st[ns][0] = MFMA16(kf, qf[0][2], st[ns][0]); st[ns][1] = MFMA16(kf, qf[1][2], st[ns][1]);
      kf = *reinterpret_cast<const short8*>(&sK[cur][rb + ((((unsigned)(5*4+lg)) ^ px) << 4)]);
      st[ns][0] = MFMA16(kf, qf[0][3], st[ns][0]); st[ns][1] = MFMA16(kf, qf[1][3], st[ns][1]);
    }

    // online softmax (natural domain); pack P^T to bf16 pairs in-register
    unsigned pb[2][4][2];
    #pragma unroll
    for (int ms = 0; ms < 2; ms++) {
      float mx = st[0][ms][0];
      #pragma unroll
      for (int ns = 0; ns < 4; ns++)
        #pragma unroll
        for (int r = 0; r < 4; r++)
          if (ns | r) mx = fmaxf(mx, st[ns][ms][r]);
      mx = fmaxf(mx, __shfl_xor(mx, 16));
      mx = fmaxf(mx, __shfl_xor(mx, 32));
      float mn = fmaxf(m_run[ms], mx);
      float sc = __expf(m_run[ms] - mn);
      m_run[ms] = mn;
      float lsum = 0.f;
      float p[4][4];
      #pragma unroll
      for (int ns = 0; ns < 4; ns++)
        #pragma unroll
        for (int r = 0; r < 4; r++) {
          p[ns][r] = __expf(st[ns][ms][r] - mn);
          lsum += p[ns][r];
        }
      lsum += __shfl_xor(lsum, 16);
      lsum += __shfl_xor(lsum, 32);
      l_run[ms] = l_run[ms] * sc + lsum;
      #pragma unroll
      for (int ds = 0; ds < 4; ds++) oacc[ms][ds] *= sc;
      #pragma unroll
      for (int ns = 0; ns < 4; ns++) {
        pb[ms][ns][0] = (unsigned)f2bf(p[ns][0]) | ((unsigned)f2bf(p[ns][1]) << 16);
        pb[ms][ns][1] = (unsigned)f2bf(p[ns][2]) | ((unsigned)f2bf(p[ns][3]) << 16);
      }
    }

    // O^T += V^T . P^T : P^T B-frags via shfl, V^T A-frags from sV
    #pragma unroll
    for (int t2 = 0; t2 < 2; t2++) {
      short8 pf[2];
      #pragma unroll
      for (int ms = 0; ms < 2; ms++) {
        unsigned lo0 = (unsigned)__shfl((int)pb[ms][t2*2  ][0], sla);
        unsigned hi0 = (unsigned)__shfl((int)pb[ms][t2*2+1][0], sla);
        unsigned lo1 = (unsigned)__shfl((int)pb[ms][t2*2  ][1], sla);
        unsigned hi1 = (unsigned)__shfl((int)pb[ms][t2*2+1][1], sla);
        unsigned lo2 = (unsigned)__shfl((int)pb[ms][t2*2  ][0], slb);
        unsigned hi2 = (unsigned)__shfl((int)pb[ms][t2*2+1][0], slb);
        unsigned lo3 = (unsigned)__shfl((int)pb[ms][t2*2  ][1], slb);
        unsigned hi3 = (unsigned)__shfl((int)pb[ms][t2*2+1][1], slb);
        bool sh = (lane & 32) != 0;
        u32x4 w;
        w[0] = sh ? hi0 : lo0;
        w[1] = sh ? hi1 : lo1;
        w[2] = sh ? hi2 : lo2;
        w[3] = sh ? hi3 : lo3;
        pf[ms] = __builtin_bit_cast(short8, w);
      }
      #pragma unroll
      for (int ds = 0; ds < 4; ds++) {
        unsigned vr = (unsigned)(ds * 16 + l15);
        short8 vf = *reinterpret_cast<const short8*>(&sV[cur][vr * 128 + ((((unsigned)(t2*4+lg)) ^ (vr & 7)) << 4)]);
        oacc[0][ds] = MFMA16(vf, pf[0], oacc[0][ds]);
        oacc[1][ds] = MFMA16(vf, pf[1], oacc[1][ds]);
      }
    }

    __syncthreads();   // drains vmcnt: next tile staged; all reads of cur done
    cur ^= 1;
  }
  #undef STAGE_KV

  // epilogue: fp32 partials. oacc[ms][ds]: m = mbase+ms*16+l15, d = ds*16+lg*4+r
  long pbase = ((long)(h * NSPLIT + sp)) * M_MISS;
  #pragma unroll
  for (int ms = 0; ms < 2; ms++) {
    int m = mbase + ms * 16 + l15;
    if (lg == 0) {
      float2 v; v.x = m_run[ms]; v.y = l_run[ms];
      *reinterpret_cast<float2*>(&ML[(pbase + m) * 2]) = v;
    }
    #pragma unroll
    for (int ds = 0; ds < 4; ds++)
      *reinterpret_cast<f32x4*>(&Opart[(pbase + m) * 64 + ds * 16 + lg * 4]) = oacc[ms][ds];
  }
}

// ---------------- merge split-KV partials, scatter to out ----------------
__global__ __launch_bounds__(256) void k_merge(
    const float* __restrict__ Opart, const float* __restrict__ ML,
    const int* __restrict__ missing, float* __restrict__ out)
{
  int g = blockIdx.x * 256 + threadIdx.x;   // HEADS*M_MISS*16
  int d4 = (g & 15) * 4;
  int row = g >> 4;
  int m = row & (M_MISS - 1), h = row >> 11;
  long b0 = (long)h * NSPLIT * M_MISS + m;
  float mm[NSPLIT], ll[NSPLIT];
  #pragma unroll
  for (int sp = 0; sp < NSPLIT; sp++) {
    float2 v = *reinterpret_cast<const float2*>(&ML[(b0 + (long)sp * M_MISS) * 2]);
    mm[sp] = v.x; ll[sp] = v.y;
  }
  float M = fmaxf(fmaxf(mm[0], mm[1]), fmaxf(mm[2], mm[3]));
  float L = 0.f;
  f32x4 o = (f32x4){0.f,0.f,0.f,0.f};
  #pragma unroll
  for (int sp = 0; sp < NSPLIT; sp++) {
    float w = __expf(mm[sp] - M);
    L += ll[sp] * w;
    f32x4 t = *reinterpret_cast<const f32x4*>(&Opart[(b0 + (long)sp * M_MISS) * 64 + d4]);
    o += t * w;
  }
  float inv = 1.0f / L;
  int orow = missing[m];
  *reinterpret_cast<f32x4*>(&out[(long)orow * EMBED + h * 64 + d4]) = o * inv;
}

extern "C" void kernel_launch(void* const* d_in, const int* in_sizes, int n_in,
                              void* d_out, int out_size, void* d_ws, size_t ws_size,
                              hipStream_t stream) {
  const float* ehr     = (const float*)d_in[0];
  const int*   exist   = (const int*)  d_in[1];
  const int*   missing = (const int*)  d_in[2];
  const float* Wq = (const float*)d_in[3];
  const float* bq = (const float*)d_in[4];
  const float* Wk = (const float*)d_in[5];
  const float* bk = (const float*)d_in[6];
  const float* Wv = (const float*)d_in[7];
  const float* bv = (const float*)d_in[8];
  const float* cooc = (const float*)d_in[9];
  float* out = (float*)d_out;

  char* ws = (char*)d_ws;
  // Wt (3.54 MB) and ehrb (12.6 MB) are dead once the GEMMs finish; both alias
  // inside Opart's 25 MB region (written later by k_attn).
  unsigned short* Wt   = (unsigned short*)(ws);                  // [0, 3,538,944)
  unsigned short* ehrb = (unsigned short*)(ws + 3538944);        // [3,538,944, 16,121,856)
  float*          Op   = (float*)(ws);                           // [0, 25,165,824)  12*4*2048*64*4
  unsigned short* Qp = (unsigned short*)(ws + 25165824);         // 12*2048*192*2 =  9,437,184
  unsigned short* Kp = (unsigned short*)(ws + 34603008);         // 12*6144*192*2 = 28,311,552
  unsigned short* Vt = (unsigned short*)(ws + 62914560);         // 12*64*6144*2  =  9,437,184
  float*          Ml = (float*)(ws + 72351744);                  // 12*4*2048*2*4 =    786,432
                                                                 // total 73,138,176 bytes

  k_prep<<<NSEC * EMBED / (256 * 8), 256, 0, stream>>>(ehr, out, ehrb);
  k_transpose_w<<<432, 256, 0, stream>>>(Wq, Wk, Wv, Wt);
  k_pack_cooc<<<(HEADS * M_MISS * 16 + 255) / 256, 256, 0, stream>>>(cooc, missing, M_MISS, Qp);
  k_pack_cooc<<<(HEADS * N_EX * 16 + 255) / 256, 256, 0, stream>>>(cooc, exist, N_EX, Kp);
  k_gemm_fused<<<672, 256, 0, stream>>>(ehrb, missing, exist, Wt, bq, bk, bv, Qp, Kp, Vt);
  k_attn<<<HEADS * NSPLIT * (M_MISS / 128), 256, 0, stream>>>(Qp, Kp, Vt, Op, Ml);
  k_merge<<<HEADS * M_MISS * 16 / 256, 256, 0, stream>>>(Op, Ml, missing, out);
}

// Round 5
// 164.710 us; speedup vs baseline: 2.9574x; 1.2933x over previous
//
#include <hip/hip_runtime.h>

typedef __attribute__((ext_vector_type(8))) short short8;
typedef __attribute__((ext_vector_type(4))) float f32x4;
typedef __attribute__((ext_vector_type(16))) float f32x16;
typedef __attribute__((ext_vector_type(4))) unsigned short us4;
typedef __attribute__((ext_vector_type(4))) unsigned int u32x4;

#define MFMA16(a,b,c) __builtin_amdgcn_mfma_f32_16x16x32_bf16(a,b,c,0,0,0)
#define MFMA32(a,b,c) __builtin_amdgcn_mfma_f32_32x32x16_bf16(a,b,c,0,0,0)

#define EMBED 768
#define HEADS 12
#define DK 64
#define M_MISS 2048
#define N_EX 6144
#define NSEC 8192
#define NSPLIT 4
#define NSL (N_EX / NSPLIT)   // 1536 keys per split
#define DPHY 192              // physical packed dim: [0,64)=proj, [64,128)=bias_hi, [128,192)=bias_lo

// direct global->LDS, 16B per lane; dest = wave-uniform base + lane*16
#define GLOAD16(g, l) __builtin_amdgcn_global_load_lds( \
    (const __attribute__((address_space(1))) unsigned int*)(g), \
    (__attribute__((address_space(3))) unsigned int*)(l), 16, 0, 0)

__device__ __forceinline__ unsigned short f2bf(float f){
  unsigned u = __builtin_bit_cast(unsigned, f);
  u += 0x7FFFu + ((u >> 16) & 1u);
  return (unsigned short)(u >> 16);
}
__device__ __forceinline__ float bf2f(unsigned short h){
  return __builtin_bit_cast(float, ((unsigned)h) << 16);
}

// ---------------- prep: out <- ehr (fp32 copy), ehrb <- bf16(ehr) ----------------
__global__ __launch_bounds__(256) void k_prep(
    const float* __restrict__ ehr, float* __restrict__ out, unsigned short* __restrict__ ehrb)
{
  int g = blockIdx.x * 256 + threadIdx.x;   // 786432 threads? no: N*E/8 threads, 8 elems each
  float4 v0 = *reinterpret_cast<const float4*>(&ehr[(long)g * 8]);
  float4 v1 = *reinterpret_cast<const float4*>(&ehr[(long)g * 8 + 4]);
  *reinterpret_cast<float4*>(&out[(long)g * 8]) = v0;
  *reinterpret_cast<float4*>(&out[(long)g * 8 + 4]) = v1;
  short8 p;
  p[0]=(short)f2bf(v0.x); p[1]=(short)f2bf(v0.y); p[2]=(short)f2bf(v0.z); p[3]=(short)f2bf(v0.w);
  p[4]=(short)f2bf(v1.x); p[5]=(short)f2bf(v1.y); p[6]=(short)f2bf(v1.z); p[7]=(short)f2bf(v1.w);
  *reinterpret_cast<short8*>(&ehrb[(long)g * 8]) = p;
}

// ---------------- transpose + cast weights: Wt[which][c][e] = W[e][c] ----------------
__global__ __launch_bounds__(256) void k_transpose_w(
    const float* __restrict__ Wq, const float* __restrict__ Wk,
    const float* __restrict__ Wv, unsigned short* __restrict__ Wt)
{
  int bid = blockIdx.x;
  int which = bid / 144, t = bid % 144;
  int er0 = (t / 12) * 64, cc0 = (t % 12) * 64;
  const float* W = (which == 0) ? Wq : ((which == 1) ? Wk : Wv);
  unsigned short* dst = Wt + (long)which * EMBED * EMBED;
  __shared__ float tile[64][65];
  int tid = threadIdx.x;
  {
    int e = tid >> 4, c4 = (tid & 15) * 4;
    for (int i = 0; i < 4; i++) {
      float4 v = *reinterpret_cast<const float4*>(&W[(long)(er0 + e + i*16) * EMBED + cc0 + c4]);
      tile[e + i*16][c4 + 0] = v.x; tile[e + i*16][c4 + 1] = v.y;
      tile[e + i*16][c4 + 2] = v.z; tile[e + i*16][c4 + 3] = v.w;
    }
  }
  __syncthreads();
  {
    int c = tid >> 4, e4 = (tid & 15) * 4;
    for (int i = 0; i < 4; i++) {
      us4 u;
      for (int j = 0; j < 4; j++) u[j] = f2bf(tile[e4 + j][c + i*16]);
      *reinterpret_cast<us4*>(&dst[(long)(cc0 + c + i*16) * EMBED + er0 + e4]) = u;
    }
  }
}

// ---------------- gather cooc_bias, hi/lo split, into dims [64,192) of Qp/Kp ----------------
__global__ __launch_bounds__(256) void k_pack_cooc(
    const float* __restrict__ cooc, const int* __restrict__ idx, int count,
    unsigned short* __restrict__ dst)
{
  int g = blockIdx.x * 256 + threadIdx.x;
  int total = HEADS * count * 16;
  if (g >= total) return;
  int d4 = (g & 15) * 4;
  int r  = (g >> 4) % count;
  int h  = (g >> 4) / count;
  int src_row = idx[r];
  float4 v = *reinterpret_cast<const float4*>(&cooc[((long)h * NSEC + src_row) * DK + d4]);
  us4 hi, lo;
  float xs[4] = {v.x, v.y, v.z, v.w};
  #pragma unroll
  for (int j = 0; j < 4; j++) {
    unsigned short hb = f2bf(xs[j]);
    hi[j] = hb;
    lo[j] = f2bf(xs[j] - bf2f(hb));
  }
  long base = ((long)h * count + r) * DPHY;
  *reinterpret_cast<us4*>(&dst[base +  64 + d4]) = hi;
  *reinterpret_cast<us4*>(&dst[base + 128 + d4]) = lo;
}

// ---------------- fused gather-GEMM (Q/K/V in one launch), gload_lds staging ----------------
__global__ __launch_bounds__(256) void k_gemm_fused(
    const unsigned short* __restrict__ ehrb,
    const int* __restrict__ missing, const int* __restrict__ exist,
    const unsigned short* __restrict__ Wt,
    const float* __restrict__ bq, const float* __restrict__ bk, const float* __restrict__ bv,
    unsigned short* __restrict__ Qp, unsigned short* __restrict__ Kp, unsigned short* __restrict__ Vt)
{
  __shared__ unsigned char sA[2][8192];   // 128 rows x 32 bf16 (64B rows), chunk-swizzled
  __shared__ unsigned char sB[2][8192];
  int bid = blockIdx.x;
  int mode, row0, col0;
  const int* idx; const unsigned short* W; const float* bias;
  if (bid < 96)       { mode = 0; idx = missing; W = Wt;              bias = bq;
                        row0 = (bid & 15) * 128; col0 = (bid >> 4) * 128; }
  else if (bid < 384) { int t = bid - 96;  mode = 1; idx = exist; W = Wt + 589824;     bias = bk;
                        row0 = (t % 48) * 128; col0 = (t / 48) * 128; }
  else                { int t = bid - 384; mode = 2; idx = exist; W = Wt + 2 * 589824; bias = bv;
                        row0 = (t % 48) * 128; col0 = (t / 48) * 128; }

  int tid = threadIdx.x;
  int wv4 = tid >> 6, lane = tid & 63, l15 = lane & 15, lg = lane >> 4;
  int wm = wv4 >> 1, wn = wv4 & 1;

  int ar = tid >> 2, sl = tid & 3;
  int aoff = (sl ^ (ar & 3)) << 3;                     // element offset within row
  long gA0 = (long)idx[row0 + ar] * EMBED + aoff;
  long gA1 = (long)idx[row0 + ar + 64] * EMBED + aoff; // (ar+64)&3 == ar&3
  long gB0 = (long)(col0 + ar) * EMBED + aoff;
  long gB1 = gB0 + (long)64 * EMBED;

  f32x4 acc[4][4];
  #pragma unroll
  for (int i = 0; i < 4; i++)
    #pragma unroll
    for (int j = 0; j < 4; j++) acc[i][j] = (f32x4){0.f,0.f,0.f,0.f};

  #define STAGE_G(buf, k0) do { \
    GLOAD16(ehrb + gA0 + (k0), &sA[buf][wv4 * 1024]); \
    GLOAD16(ehrb + gA1 + (k0), &sA[buf][4096 + wv4 * 1024]); \
    GLOAD16(W + gB0 + (k0), &sB[buf][wv4 * 1024]); \
    GLOAD16(W + gB1 + (k0), &sB[buf][4096 + wv4 * 1024]); \
  } while (0)

  STAGE_G(0, 0);
  __syncthreads();
  int cur = 0;
  for (int ks = 0; ks < 24; ks++) {
    if (ks < 23) STAGE_G(cur ^ 1, (ks + 1) * 32);
    short8 a[4], b[4];
    #pragma unroll
    for (int i = 0; i < 4; i++) {
      unsigned r = (unsigned)(wm * 64 + 16 * i + l15);
      a[i] = *reinterpret_cast<const short8*>(&sA[cur][r * 64 + (((unsigned)lg ^ (r & 3)) << 4)]);
      unsigned c = (unsigned)(wn * 64 + 16 * i + l15);
      b[i] = *reinterpret_cast<const short8*>(&sB[cur][c * 64 + (((unsigned)lg ^ (c & 3)) << 4)]);
    }
    #pragma unroll
    for (int i = 0; i < 4; i++)
      #pragma unroll
      for (int j = 0; j < 4; j++)
        acc[i][j] = MFMA16(a[i], b[j], acc[i][j]);
    __syncthreads();
    cur ^= 1;
  }
  #undef STAGE_G

  #pragma unroll
  for (int i = 0; i < 4; i++) {
    int mrow = row0 + wm * 64 + 16 * i + lg * 4;
    #pragma unroll
    for (int j = 0; j < 4; j++) {
      int cg = col0 + wn * 64 + 16 * j + l15;
      float bv_ = bias[cg];
      int h = cg >> 6, d = cg & 63;
      if (mode == 2) {
        us4 u;
        #pragma unroll
        for (int r = 0; r < 4; r++) u[r] = f2bf(acc[i][j][r] + bv_);
        *reinterpret_cast<us4*>(&Vt[((long)h * 64 + d) * N_EX + mrow]) = u;
      } else if (mode == 0) {
        #pragma unroll
        for (int r = 0; r < 4; r++)
          Qp[((long)h * M_MISS + mrow + r) * DPHY + d] = f2bf((acc[i][j][r] + bv_) * 0.125f);
      } else {
        #pragma unroll
        for (int r = 0; r < 4; r++)
          Kp[((long)h * N_EX + mrow + r) * DPHY + d] = f2bf(acc[i][j][r] + bv_);
      }
    }
  }
}

// ---------------- flash attention: swapped 32x32 MFMA, in-register softmax ----------------
// grid 768 = 12h x 4sp x 16qb, 4 waves x 32 q-rows. KVBLK=64, 24 iters, 32KB LDS.
// S^T = K'.Q'^T via mfma_32x32x16: lane owns q-row m=lane&31 -> softmax needs only
// shfl_xor(32). P packed in-register (v_cvt_pk_bf16_f32), PV = V^T.P^T (O^T, m=lane&31).
__global__ __launch_bounds__(256, 3) void k_attn(
    const unsigned short* __restrict__ Qp, const unsigned short* __restrict__ Kp,
    const unsigned short* __restrict__ Vt,
    float* __restrict__ Opart, float* __restrict__ ML)
{
  // XCD-chunked swizzle: 768 = 8 XCDs x 96; consecutive wg share (h,sp) K/V slice
  int wg = (blockIdx.x & 7) * 96 + (blockIdx.x >> 3);
  int h  = wg >> 6;
  int sp = (wg >> 4) & 3;
  int qb = wg & 15;
  int tid = threadIdx.x;
  int wv = tid >> 6, lane = tid & 63, l31 = lane & 31, hh = lane >> 5;

  __shared__ unsigned char sK[64 * 384];   // 64 n-rows x 192 bf16 (24 chunks), swizzled: 24KB
  __shared__ unsigned char sV[64 * 128];   // 64 d-rows x  64 bf16 ( 8 chunks), swizzled:  8KB

  // staging: chunk s = i*256+tid -> (row, slot); LDS linear, source pre-swizzled
  int koff[6];
  #pragma unroll
  for (int i = 0; i < 6; i++) {
    int s = i * 256 + tid;
    int row = s / 24, slt = s - row * 24;
    koff[i] = row * DPHY + ((slt ^ (row & 7)) << 3);
  }
  int voff[2];
  #pragma unroll
  for (int i = 0; i < 2; i++) {
    int s = i * 256 + tid;
    int row = s >> 3, slt = s & 7;
    voff[i] = row * N_EX + ((slt ^ (row & 7)) << 3);
  }
  const unsigned short* kti0 = Kp + ((long)h * N_EX + sp * NSL) * DPHY;
  const unsigned short* vti0 = Vt + (long)h * 64 * N_EX + sp * NSL;

  int mbase = qb * 128 + wv * 32;
  int m = mbase + l31;

  // Q'^T B-frags: col=m=lane&31, k=hh*8+e. 12 phys 16-dim groups (48 VGPR).
  short8 qg[12];
  {
    const unsigned short* qrow = Qp + ((long)h * M_MISS + m) * DPHY + hh * 8;
    #pragma unroll
    for (int g = 0; g < 12; g++)
      qg[g] = *reinterpret_cast<const short8*>(qrow + g * 16);
  }

  f32x16 oacc[2];
  #pragma unroll
  for (int dt = 0; dt < 2; dt++)
    #pragma unroll
    for (int r = 0; r < 16; r++) oacc[dt][r] = 0.f;
  float m_run = -3.0e38f, l_run = 0.f;

  for (int it = 0; it < NSL / 64; ++it) {
    __syncthreads();   // all waves done reading previous tile
    {
      const unsigned short* kt_ = kti0 + (long)it * 64 * DPHY;
      GLOAD16(kt_ + koff[0], &sK[(0 * 4 + wv) * 1024]);
      GLOAD16(kt_ + koff[1], &sK[(1 * 4 + wv) * 1024]);
      GLOAD16(kt_ + koff[2], &sK[(2 * 4 + wv) * 1024]);
      GLOAD16(kt_ + koff[3], &sK[(3 * 4 + wv) * 1024]);
      GLOAD16(kt_ + koff[4], &sK[(4 * 4 + wv) * 1024]);
      GLOAD16(kt_ + koff[5], &sK[(5 * 4 + wv) * 1024]);
      const unsigned short* vt_ = vti0 + it * 64;
      GLOAD16(vt_ + voff[0], &sV[(0 * 4 + wv) * 1024]);
      GLOAD16(vt_ + voff[1], &sV[(1 * 4 + wv) * 1024]);
    }
    __syncthreads();   // drains vmcnt: tile ready

    // S^T: 2 n-tiles of 32 rows. A = K chunk (row n=l31), B = qg (col m=l31).
    // pairing: g0-3 proj.proj, g4-7 hi.hi, (k4..k7).qlo = hi.lo, g8-11.qhi = lo.hi
    f32x16 st[2];
    #pragma unroll
    for (int nt = 0; nt < 2; nt++) {
      #pragma unroll
      for (int r = 0; r < 16; r++) st[nt][r] = 0.f;
      unsigned nrow = (unsigned)(nt * 32 + l31);
      const unsigned char* kb = &sK[nrow * 384];
      unsigned px = nrow & 7;
      #define KRD(g) (*reinterpret_cast<const short8*>(kb + ((((unsigned)(2*(g)+hh)) ^ px) << 4)))
      short8 kf;
      kf = KRD(0); st[nt] = MFMA32(kf, qg[0], st[nt]);
      kf = KRD(1); st[nt] = MFMA32(kf, qg[1], st[nt]);
      kf = KRD(2); st[nt] = MFMA32(kf, qg[2], st[nt]);
      kf = KRD(3); st[nt] = MFMA32(kf, qg[3], st[nt]);
      short8 k4 = KRD(4), k5 = KRD(5), k6 = KRD(6), k7 = KRD(7);
      st[nt] = MFMA32(k4, qg[4], st[nt]);
      st[nt] = MFMA32(k5, qg[5], st[nt]);
      st[nt] = MFMA32(k6, qg[6], st[nt]);
      st[nt] = MFMA32(k7, qg[7], st[nt]);
      st[nt] = MFMA32(k4, qg[8], st[nt]);
      st[nt] = MFMA32(k5, qg[9], st[nt]);
      st[nt] = MFMA32(k6, qg[10], st[nt]);
      st[nt] = MFMA32(k7, qg[11], st[nt]);
      kf = KRD(8);  st[nt] = MFMA32(kf, qg[4], st[nt]);
      kf = KRD(9);  st[nt] = MFMA32(kf, qg[5], st[nt]);
      kf = KRD(10); st[nt] = MFMA32(kf, qg[6], st[nt]);
      kf = KRD(11); st[nt] = MFMA32(kf, qg[7], st[nt]);
      #undef KRD
    }

    // in-register online softmax: lane holds 32 of 64 n-values for its q-row m.
    float mx = st[0][0];
    #pragma unroll
    for (int r = 1; r < 16; r++) mx = fmaxf(mx, st[0][r]);
    #pragma unroll
    for (int r = 0; r < 16; r++) mx = fmaxf(mx, st[1][r]);
    mx = fmaxf(mx, __shfl_xor(mx, 32));
    float mn = fmaxf(m_run, mx);
    float sc = __expf(m_run - mn);
    m_run = mn;
    float lsum = 0.f;
    unsigned c[2][4][2];   // c[nt][jj][i] = bf16pair P(nt*32+8jj+4hh+2i, +1)
    #pragma unroll
    for (int nt = 0; nt < 2; nt++) {
      float p[16];
      #pragma unroll
      for (int r = 0; r < 16; r++) { p[r] = __expf(st[nt][r] - mn); lsum += p[r]; }
      #pragma unroll
      for (int jj = 0; jj < 4; jj++) {
        asm("v_cvt_pk_bf16_f32 %0, %1, %2" : "=v"(c[nt][jj][0]) : "v"(p[4*jj+0]), "v"(p[4*jj+1]));
        asm("v_cvt_pk_bf16_f32 %0, %1, %2" : "=v"(c[nt][jj][1]) : "v"(p[4*jj+2]), "v"(p[4*jj+3]));
      }
    }
    lsum += __shfl_xor(lsum, 32);
    l_run = l_run * sc + lsum;
    #pragma unroll
    for (int dt = 0; dt < 2; dt++)
      #pragma unroll
      for (int r = 0; r < 16; r++) oacc[dt][r] *= sc;

    // P^T B-frags: lane needs P(n = nt*32+ks*16+hh*8+e); half local, half from lane^32
    short8 pf[2][2];
    #pragma unroll
    for (int nt = 0; nt < 2; nt++)
      #pragma unroll
      for (int ks = 0; ks < 2; ks++) {
        unsigned s0 = hh ? c[nt][2*ks][0] : c[nt][2*ks+1][0];
        unsigned s1 = hh ? c[nt][2*ks][1] : c[nt][2*ks+1][1];
        unsigned r0 = (unsigned)__shfl_xor((int)s0, 32);
        unsigned r1 = (unsigned)__shfl_xor((int)s1, 32);
        u32x4 w;
        w[0] = hh ? r0 : c[nt][2*ks][0];
        w[1] = hh ? r1 : c[nt][2*ks][1];
        w[2] = hh ? c[nt][2*ks+1][0] : r0;
        w[3] = hh ? c[nt][2*ks+1][1] : r1;
        pf[nt][ks] = __builtin_bit_cast(short8, w);
      }

    // O^T += V^T . P^T : A = V^T (row d=l31), B = pf. 8 MFMAs.
    #pragma unroll
    for (int dt = 0; dt < 2; dt++) {
      unsigned drow = (unsigned)(dt * 32 + l31);
      const unsigned char* vb = &sV[drow * 128];
      unsigned pd = drow & 7;
      #pragma unroll
      for (int nt = 0; nt < 2; nt++)
        #pragma unroll
        for (int ks = 0; ks < 2; ks++) {
          short8 vf = *reinterpret_cast<const short8*>(vb + ((((unsigned)(nt*4+ks*2+hh)) ^ pd) << 4));
          oacc[dt] = MFMA32(vf, pf[nt][ks], oacc[dt]);
        }
    }
  }

  // epilogue: O^T reg r -> d = dt*32 + 8*(r>>2) + 4*hh + (r&3); m = mbase+l31
  long pbase = ((long)(h * NSPLIT + sp)) * M_MISS;
  if (hh == 0) {
    float2 v; v.x = m_run; v.y = l_run;
    *reinterpret_cast<float2*>(&ML[(pbase + m) * 2]) = v;
  }
  #pragma unroll
  for (int dt = 0; dt < 2; dt++)
    #pragma unroll
    for (int rq = 0; rq < 4; rq++) {
      f32x4 o4;
      o4[0] = oacc[dt][4*rq + 0]; o4[1] = oacc[dt][4*rq + 1];
      o4[2] = oacc[dt][4*rq + 2]; o4[3] = oacc[dt][4*rq + 3];
      *reinterpret_cast<f32x4*>(&Opart[(pbase + m) * 64 + dt * 32 + 8 * rq + 4 * hh]) = o4;
    }
}

// ---------------- merge split-KV partials, scatter to out ----------------
__global__ __launch_bounds__(256) void k_merge(
    const float* __restrict__ Opart, const float* __restrict__ ML,
    const int* __restrict__ missing, float* __restrict__ out)
{
  int g = blockIdx.x * 256 + threadIdx.x;   // HEADS*M_MISS*16
  int d4 = (g & 15) * 4;
  int row = g >> 4;
  int m = row & (M_MISS - 1), h = row >> 11;
  long b0 = (long)h * NSPLIT * M_MISS + m;
  float mm[NSPLIT], ll[NSPLIT];
  #pragma unroll
  for (int sp = 0; sp < NSPLIT; sp++) {
    float2 v = *reinterpret_cast<const float2*>(&ML[(b0 + (long)sp * M_MISS) * 2]);
    mm[sp] = v.x; ll[sp] = v.y;
  }
  float M = fmaxf(fmaxf(mm[0], mm[1]), fmaxf(mm[2], mm[3]));
  float L = 0.f;
  f32x4 o = (f32x4){0.f,0.f,0.f,0.f};
  #pragma unroll
  for (int sp = 0; sp < NSPLIT; sp++) {
    float w = __expf(mm[sp] - M);
    L += ll[sp] * w;
    f32x4 t = *reinterpret_cast<const f32x4*>(&Opart[(b0 + (long)sp * M_MISS) * 64 + d4]);
    o += t * w;
  }
  float inv = 1.0f / L;
  int orow = missing[m];
  *reinterpret_cast<f32x4*>(&out[(long)orow * EMBED + h * 64 + d4]) = o * inv;
}

extern "C" void kernel_launch(void* const* d_in, const int* in_sizes, int n_in,
                              void* d_out, int out_size, void* d_ws, size_t ws_size,
                              hipStream_t stream) {
  const float* ehr     = (const float*)d_in[0];
  const int*   exist   = (const int*)  d_in[1];
  const int*   missing = (const int*)  d_in[2];
  const float* Wq = (const float*)d_in[3];
  const float* bq = (const float*)d_in[4];
  const float* Wk = (const float*)d_in[5];
  const float* bk = (const float*)d_in[6];
  const float* Wv = (const float*)d_in[7];
  const float* bv = (const float*)d_in[8];
  const float* cooc = (const float*)d_in[9];
  float* out = (float*)d_out;

  char* ws = (char*)d_ws;
  // Wt (3.54 MB) and ehrb (12.6 MB) are dead once the GEMMs finish; both alias
  // inside Opart's 25 MB region (written later by k_attn).
  unsigned short* Wt   = (unsigned short*)(ws);                  // [0, 3,538,944)
  unsigned short* ehrb = (unsigned short*)(ws + 3538944);        // [3,538,944, 16,121,856)
  float*          Op   = (float*)(ws);                           // [0, 25,165,824)  12*4*2048*64*4
  unsigned short* Qp = (unsigned short*)(ws + 25165824);         // 12*2048*192*2 =  9,437,184
  unsigned short* Kp = (unsigned short*)(ws + 34603008);         // 12*6144*192*2 = 28,311,552
  unsigned short* Vt = (unsigned short*)(ws + 62914560);         // 12*64*6144*2  =  9,437,184
  float*          Ml = (float*)(ws + 72351744);                  // 12*4*2048*2*4 =    786,432
                                                                 // total 73,138,176 bytes

  k_prep<<<NSEC * EMBED / (256 * 8), 256, 0, stream>>>(ehr, out, ehrb);
  k_transpose_w<<<432, 256, 0, stream>>>(Wq, Wk, Wv, Wt);
  k_pack_cooc<<<(HEADS * M_MISS * 16 + 255) / 256, 256, 0, stream>>>(cooc, missing, M_MISS, Qp);
  k_pack_cooc<<<(HEADS * N_EX * 16 + 255) / 256, 256, 0, stream>>>(cooc, exist, N_EX, Kp);
  k_gemm_fused<<<672, 256, 0, stream>>>(ehrb, missing, exist, Wt, bq, bk, bv, Qp, Kp, Vt);
  k_attn<<<HEADS * NSPLIT * (M_MISS / 128), 256, 0, stream>>>(Qp, Kp, Vt, Op, Ml);
  k_merge<<<HEADS * M_MISS * 16 / 256, 256, 0, stream>>>(Op, Ml, missing, out);
}